// Round 1
// baseline (273.330 us; speedup 1.0000x reference)
//
#include <hip/hip_runtime.h>
#include <stdint.h>

typedef unsigned short u16;
typedef __attribute__((ext_vector_type(8))) unsigned short ushort8;
typedef __attribute__((ext_vector_type(4))) unsigned short ushort4v;
typedef __attribute__((ext_vector_type(8))) __bf16 bf16x8;
typedef __attribute__((ext_vector_type(4))) float f32x4;

__device__ __forceinline__ u16 f2bf(float f) {
    union { float f; unsigned int u; } v; v.f = f;
    unsigned int r = v.u + 0x7FFFu + ((v.u >> 16) & 1u);   // RNE
    return (u16)(r >> 16);
}
__device__ __forceinline__ float bf2f(u16 b) {
    union { unsigned int u; float f; } v; v.u = ((unsigned int)b) << 16;
    return v.f;
}

typedef __attribute__((address_space(1))) const uint32_t* gptr_t;
typedef __attribute__((address_space(3))) uint32_t* lptr_t;
__device__ __forceinline__ void async_copy16(const void* g, void* l) {
    __builtin_amdgcn_global_load_lds((gptr_t)g, (lptr_t)l, 16, 0, 0);
}

// ---------------- conversions ----------------

__global__ __launch_bounds__(256) void f32_to_bf16_kernel(
    const float* __restrict__ in, u16* __restrict__ out, int n8)
{
    int i = blockIdx.x * 256 + threadIdx.x;
    if (i >= n8) return;
    const float4* p = (const float4*)(in + (size_t)i * 8);
    float4 x0 = p[0], x1 = p[1];
    ushort8 o;
    o[0] = f2bf(x0.x); o[1] = f2bf(x0.y); o[2] = f2bf(x0.z); o[3] = f2bf(x0.w);
    o[4] = f2bf(x1.x); o[5] = f2bf(x1.y); o[6] = f2bf(x1.z); o[7] = f2bf(x1.w);
    *(ushort8*)(out + (size_t)i * 8) = o;
}

__global__ __launch_bounds__(256) void binarize_kernel(
    const float* __restrict__ in, u16* __restrict__ out, int n8)
{
    int i = blockIdx.x * 256 + threadIdx.x;
    if (i >= n8) return;
    const float4* p = (const float4*)(in + (size_t)i * 8);
    float4 x0 = p[0], x1 = p[1];
    ushort8 o;
    o[0] = x0.x >= 0.f ? 0x3F80 : 0xBF80;
    o[1] = x0.y >= 0.f ? 0x3F80 : 0xBF80;
    o[2] = x0.z >= 0.f ? 0x3F80 : 0xBF80;
    o[3] = x0.w >= 0.f ? 0x3F80 : 0xBF80;
    o[4] = x1.x >= 0.f ? 0x3F80 : 0xBF80;
    o[5] = x1.y >= 0.f ? 0x3F80 : 0xBF80;
    o[6] = x1.z >= 0.f ? 0x3F80 : 0xBF80;
    o[7] = x1.w >= 0.f ? 0x3F80 : 0xBF80;
    *(ushort8*)(out + (size_t)i * 8) = o;
}

// W4 [10][1024] f32 -> W4T [1024][16] bf16 (cols 10..15 zero)
__global__ __launch_bounds__(256) void build_w4t(
    const float* __restrict__ W4, u16* __restrict__ W4T)
{
    int idx = blockIdx.x * 256 + threadIdx.x;   // 16384 total
    int k = idx >> 4, c = idx & 15;
    u16 v = 0;
    if (c < 10) v = (W4[(size_t)c * 1024 + k] >= 0.f) ? 0x3F80 : 0xBF80;
    W4T[idx] = v;
}

// ---------------- GEMM: C = relu(A @ B^T), A[M,K] bf16, B[N,K] bf16, C[M,N] f32 ----------------

#define BM 128
#define BN 128
#define BK 64

__global__ __launch_bounds__(256) void gemm_bt_relu(
    const u16* __restrict__ A, const u16* __restrict__ B,
    float* __restrict__ C, int M, int N, int K)
{
    __shared__ __align__(16) u16 As[BM * BK];
    __shared__ __align__(16) u16 Bs[BN * BK];

    const int tid  = threadIdx.x;
    const int wid  = tid >> 6;
    const int lane = tid & 63;
    const int row0 = blockIdx.x * BM;
    const int col0 = blockIdx.y * BN;

    const int wm = (wid >> 1) * 64;   // wave's M offset in tile
    const int wn = (wid & 1) * 64;    // wave's N offset in tile

    f32x4 acc[4][4];
    #pragma unroll
    for (int i = 0; i < 4; i++)
        #pragma unroll
        for (int j = 0; j < 4; j++)
            acc[i][j] = (f32x4){0.f, 0.f, 0.f, 0.f};

    // staging: each thread covers 16B = 8 elems; 256 thr = 32 rows per step
    const int s_r = wid * 8 + (lane >> 3);
    const int s_c = (lane & 7) * 8;

    const int lr = lane & 15;
    const int lk = (lane >> 4) * 8;

    for (int k0 = 0; k0 < K; k0 += BK) {
        #pragma unroll
        for (int it = 0; it < 4; ++it) {
            int ra = row0 + it * 32 + s_r;
            int rb = col0 + it * 32 + s_r;
            async_copy16(A + (size_t)ra * K + k0 + s_c, As + it * 2048 + wid * 512);
            async_copy16(B + (size_t)rb * K + k0 + s_c, Bs + it * 2048 + wid * 512);
        }
        __syncthreads();   // drains vmcnt (compiler emits waitcnt before barrier)

        const u16* pa = &As[(wm + lr) * BK + lk];
        const u16* pb = &Bs[(wn + lr) * BK + lk];
        #pragma unroll
        for (int kk = 0; kk < 2; ++kk) {
            bf16x8 a[4], b[4];
            #pragma unroll
            for (int i = 0; i < 4; i++)
                a[i] = *(const bf16x8*)(pa + i * 16 * BK + kk * 32);
            #pragma unroll
            for (int j = 0; j < 4; j++)
                b[j] = *(const bf16x8*)(pb + j * 16 * BK + kk * 32);
            #pragma unroll
            for (int i = 0; i < 4; i++)
                #pragma unroll
                for (int j = 0; j < 4; j++)
                    acc[i][j] = __builtin_amdgcn_mfma_f32_16x16x32_bf16(
                        a[i], b[j], acc[i][j], 0, 0, 0);
        }
        __syncthreads();
    }

    // epilogue: D[row=(lane>>4)*4+reg][col=lane&15]  (measured m89/m91)
    const int er = (lane >> 4) * 4;
    const int ec = lane & 15;
    #pragma unroll
    for (int i = 0; i < 4; i++) {
        #pragma unroll
        for (int j = 0; j < 4; j++) {
            int r = row0 + wm + i * 16 + er;
            int c = col0 + wn + j * 16 + ec;
            f32x4 v = acc[i][j];
            #pragma unroll
            for (int b = 0; b < 4; b++) {
                float x = v[b];
                C[(size_t)(r + b) * N + c] = x > 0.f ? x : 0.f;
            }
        }
    }
}

// ---------------- BatchNorm (training-mode, biased var) ----------------

// partial sums: grid (4, 128), 64 rows per block
__global__ __launch_bounds__(256) void bn_partial(
    const float* __restrict__ H, float* __restrict__ part)
{
    int c  = blockIdx.x * 256 + threadIdx.x;
    int r0 = blockIdx.y * 64;
    float s = 0.f, s2 = 0.f;
    #pragma unroll 8
    for (int r = 0; r < 64; ++r) {
        float v = H[(size_t)(r0 + r) * 1024 + c];
        s += v; s2 += v * v;
    }
    part[(size_t)blockIdx.y * 1024 + c] = s;
    part[131072 + (size_t)blockIdx.y * 1024 + c] = s2;
}

// finalize: scale/shift per column. grid 4
__global__ __launch_bounds__(256) void bn_finalize(
    const float* __restrict__ part, const float* __restrict__ gamma,
    const float* __restrict__ beta, float* __restrict__ ss)
{
    int c = blockIdx.x * 256 + threadIdx.x;
    float s = 0.f, s2 = 0.f;
    for (int i = 0; i < 128; ++i) {
        s  += part[(size_t)i * 1024 + c];
        s2 += part[131072 + (size_t)i * 1024 + c];
    }
    float mean = s * (1.0f / 8192.0f);
    float var  = fmaxf(s2 * (1.0f / 8192.0f) - mean * mean, 0.f);
    float sc   = gamma[c] * rsqrtf(var + 1e-5f);
    ss[c]        = sc;
    ss[1024 + c] = beta[c] - mean * sc;
}

// apply: A_bf16 = bf16(H*scale + shift). grid 8192, 4 elems/thread
__global__ __launch_bounds__(256) void bn_apply(
    const float* __restrict__ H, const float* __restrict__ ss,
    u16* __restrict__ Aout)
{
    int i = blockIdx.x * 256 + threadIdx.x;     // group of 4
    int c = (i * 4) & 1023;
    float4 h  = *(const float4*)(H + (size_t)i * 4);
    float4 sc = *(const float4*)(ss + c);
    float4 sh = *(const float4*)(ss + 1024 + c);
    ushort4v o;
    o[0] = f2bf(h.x * sc.x + sh.x);
    o[1] = f2bf(h.y * sc.y + sh.y);
    o[2] = f2bf(h.z * sc.z + sh.z);
    o[3] = f2bf(h.w * sc.w + sh.w);
    *(ushort4v*)(Aout + (size_t)i * 4) = o;
}

// ---------------- head: out[8192,10] = A @ W4T (K=1024), no relu ----------------

__global__ __launch_bounds__(256) void head_kernel(
    const u16* __restrict__ A, const u16* __restrict__ W4T,
    float* __restrict__ out)
{
    const int lane = threadIdx.x & 63;
    const int wid  = threadIdx.x >> 6;
    const int r    = blockIdx.x * 4 + wid;

    float acc[10];
    #pragma unroll
    for (int c = 0; c < 10; c++) acc[c] = 0.f;

    #pragma unroll
    for (int j = 0; j < 16; ++j) {
        int k = j * 64 + lane;
        float a = bf2f(A[(size_t)r * 1024 + k]);
        ushort8 w0 = *(const ushort8*)(W4T + (size_t)k * 16);
        acc[0] += a * bf2f(w0[0]); acc[1] += a * bf2f(w0[1]);
        acc[2] += a * bf2f(w0[2]); acc[3] += a * bf2f(w0[3]);
        acc[4] += a * bf2f(w0[4]); acc[5] += a * bf2f(w0[5]);
        acc[6] += a * bf2f(w0[6]); acc[7] += a * bf2f(w0[7]);
        u16 w8 = W4T[(size_t)k * 16 + 8];
        u16 w9 = W4T[(size_t)k * 16 + 9];
        acc[8] += a * bf2f(w8);    acc[9] += a * bf2f(w9);
    }
    #pragma unroll
    for (int c = 0; c < 10; c++) {
        float s = acc[c];
        #pragma unroll
        for (int off = 32; off > 0; off >>= 1) s += __shfl_xor(s, off, 64);
        acc[c] = s;
    }
    if (lane == 0) {
        #pragma unroll
        for (int c = 0; c < 10; c++) out[(size_t)r * 10 + c] = acc[c];
    }
}

// ---------------- launch ----------------

extern "C" void kernel_launch(void* const* d_in, const int* in_sizes, int n_in,
                              void* d_out, int out_size, void* d_ws, size_t ws_size,
                              hipStream_t stream) {
    const float* x  = (const float*)d_in[0];
    const float* W1 = (const float*)d_in[1];
    const float* W2 = (const float*)d_in[2];
    const float* W3 = (const float*)d_in[3];
    const float* W4 = (const float*)d_in[4];
    const float* g1 = (const float*)d_in[5];
    const float* b1 = (const float*)d_in[6];
    const float* g2 = (const float*)d_in[7];
    const float* b2 = (const float*)d_in[8];
    const float* g3 = (const float*)d_in[9];
    const float* b3 = (const float*)d_in[10];
    float* out = (float*)d_out;

    char* ws = (char*)d_ws;
    // layout (bytes):
    u16*   Xb   = (u16*)  (ws + 0);           // 50,331,648  (x bf16; reused as A after GEMM1)
    float* H    = (float*)(ws + 50331648);    // 33,554,432
    u16*   W1b  = (u16*)  (ws + 83886080);    //  6,291,456
    u16*   W2b  = (u16*)  (ws + 90177536);    //  2,097,152
    u16*   W3b  = (u16*)  (ws + 92274688);    //  2,097,152
    u16*   W4T  = (u16*)  (ws + 94371840);    //     32,768
    float* part = (float*)(ws + 94404608);    //  1,048,576
    float* ss   = (float*)(ws + 95453184);    //      8,192
    u16*   A    = Xb;                         // normalized activations [8192][1024] bf16

    // pre-passes
    f32_to_bf16_kernel<<<12288, 256, 0, stream>>>(x, Xb, 3145728);
    binarize_kernel<<<1536, 256, 0, stream>>>(W1, W1b, 393216);
    binarize_kernel<<<512, 256, 0, stream>>>(W2, W2b, 131072);
    binarize_kernel<<<512, 256, 0, stream>>>(W3, W3b, 131072);
    build_w4t<<<64, 256, 0, stream>>>(W4, W4T);

    dim3 gemm_grid(64, 8);   // M/128, N/128
    dim3 bn_grid(4, 128);

    // layer 1
    gemm_bt_relu<<<gemm_grid, 256, 0, stream>>>(Xb, W1b, H, 8192, 1024, 3072);
    bn_partial<<<bn_grid, 256, 0, stream>>>(H, part);
    bn_finalize<<<4, 256, 0, stream>>>(part, g1, b1, ss);
    bn_apply<<<8192, 256, 0, stream>>>(H, ss, A);

    // layer 2
    gemm_bt_relu<<<gemm_grid, 256, 0, stream>>>(A, W2b, H, 8192, 1024, 1024);
    bn_partial<<<bn_grid, 256, 0, stream>>>(H, part);
    bn_finalize<<<4, 256, 0, stream>>>(part, g2, b2, ss);
    bn_apply<<<8192, 256, 0, stream>>>(H, ss, A);

    // layer 3
    gemm_bt_relu<<<gemm_grid, 256, 0, stream>>>(A, W3b, H, 8192, 1024, 1024);
    bn_partial<<<bn_grid, 256, 0, stream>>>(H, part);
    bn_finalize<<<4, 256, 0, stream>>>(part, g3, b3, ss);
    bn_apply<<<8192, 256, 0, stream>>>(H, ss, A);

    // head
    head_kernel<<<2048, 256, 0, stream>>>(A, W4T, out);
}

// Round 2
// 211.176 us; speedup vs baseline: 1.2943x; 1.2943x over previous
//
#include <hip/hip_runtime.h>
#include <stdint.h>

typedef unsigned short u16;
typedef __attribute__((ext_vector_type(8))) unsigned short ushort8;
typedef __attribute__((ext_vector_type(8))) __bf16 bf16x8;
typedef __attribute__((ext_vector_type(4))) float f32x4;

__device__ __forceinline__ u16 f2bf(float f) {
    union { float f; unsigned int u; } v; v.f = f;
    unsigned int r = v.u + 0x7FFFu + ((v.u >> 16) & 1u);   // RNE
    return (u16)(r >> 16);
}
__device__ __forceinline__ float bf2f(u16 b) {
    union { unsigned int u; float f; } v; v.u = ((unsigned int)b) << 16;
    return v.f;
}

typedef __attribute__((address_space(1))) const uint32_t* gptr_t;
typedef __attribute__((address_space(3))) uint32_t* lptr_t;
__device__ __forceinline__ void async_copy16(const void* g, void* l) {
    __builtin_amdgcn_global_load_lds((gptr_t)g, (lptr_t)l, 16, 0, 0);
}

// ---------------- conversions ----------------

__global__ __launch_bounds__(256) void f32_to_bf16_kernel(
    const float* __restrict__ in, u16* __restrict__ out, int n8)
{
    int i = blockIdx.x * 256 + threadIdx.x;
    if (i >= n8) return;
    const float4* p = (const float4*)(in + (size_t)i * 8);
    float4 x0 = p[0], x1 = p[1];
    ushort8 o;
    o[0] = f2bf(x0.x); o[1] = f2bf(x0.y); o[2] = f2bf(x0.z); o[3] = f2bf(x0.w);
    o[4] = f2bf(x1.x); o[5] = f2bf(x1.y); o[6] = f2bf(x1.z); o[7] = f2bf(x1.w);
    *(ushort8*)(out + (size_t)i * 8) = o;
}

__global__ __launch_bounds__(256) void binarize_kernel(
    const float* __restrict__ in, u16* __restrict__ out, int n8)
{
    int i = blockIdx.x * 256 + threadIdx.x;
    if (i >= n8) return;
    const float4* p = (const float4*)(in + (size_t)i * 8);
    float4 x0 = p[0], x1 = p[1];
    ushort8 o;
    o[0] = x0.x >= 0.f ? 0x3F80 : 0xBF80;
    o[1] = x0.y >= 0.f ? 0x3F80 : 0xBF80;
    o[2] = x0.z >= 0.f ? 0x3F80 : 0xBF80;
    o[3] = x0.w >= 0.f ? 0x3F80 : 0xBF80;
    o[4] = x1.x >= 0.f ? 0x3F80 : 0xBF80;
    o[5] = x1.y >= 0.f ? 0x3F80 : 0xBF80;
    o[6] = x1.z >= 0.f ? 0x3F80 : 0xBF80;
    o[7] = x1.w >= 0.f ? 0x3F80 : 0xBF80;
    *(ushort8*)(out + (size_t)i * 8) = o;
}

// W4 [10][1024] f32 -> W4T [1024][16] bf16 (cols 10..15 zero)
__global__ __launch_bounds__(256) void build_w4t(
    const float* __restrict__ W4, u16* __restrict__ W4T)
{
    int idx = blockIdx.x * 256 + threadIdx.x;   // 16384 total
    int k = idx >> 4, c = idx & 15;
    u16 v = 0;
    if (c < 10) v = (W4[(size_t)c * 1024 + k] >= 0.f) ? 0x3F80 : 0xBF80;
    W4T[idx] = v;
}

// ---------------- GEMM: H = bf16(relu(A @ B^T)) ----------------
// A[M,K] bf16, B[N,K] bf16, H[M,N] bf16.
// 128x128 tile, BK=64, 4 waves (2Mx2N, 64x64 per wave), double-buffered LDS,
// counted vmcnt (2 tiles in flight), T2 XOR-swizzle (c8 ^= row&7, 16B blocks).

__global__ __launch_bounds__(256) void gemm_bt_relu_bn(
    const u16* __restrict__ A, const u16* __restrict__ B,
    u16* __restrict__ H, int M, int N, int K)
{
    __shared__ __align__(16) u16 As[2][128 * 64];
    __shared__ __align__(16) u16 Bs[2][128 * 64];

    const int tid  = threadIdx.x;
    const int wid  = tid >> 6;
    const int lane = tid & 63;
    const int lr   = lane & 15;        // fragment row-within-16
    const int hk   = lane >> 4;        // k-subblock 0..3
    const int x7   = lr & 7;           // swizzle key = row&7 (rows stride 16 -> &7 == lr&7)
    const int wr   = wid >> 1;         // wave M index (0..1)
    const int wc   = wid & 1;          // wave N index (0..1)
    const int row0 = blockIdx.x * 128;
    const int col0 = blockIdx.y * 128;

    // --- staging: 256 thr x 16B = 4KB/round = 32 rows; 4 rounds per 128x64 tile
    // linear LDS dest; global SOURCE col pre-swizzled: c8_src = (tid&7) ^ (src_row&7)
    const int s_r = tid >> 3;                                 // 0..31
    const int s_c = (((tid & 7) ^ (s_r & 7)) << 3);           // element col offset
    const u16* gA = A + (size_t)(row0 + s_r) * K + s_c;
    const u16* gB = B + (size_t)(col0 + s_r) * K + s_c;

    // --- ds_read addresses (swizzled): elem = row*64 + ((c8 ^ (row&7))*8
    int a_base[4], b_base[4];
    #pragma unroll
    for (int i = 0; i < 4; ++i) a_base[i] = (wr * 64 + i * 16 + lr) * 64;
    #pragma unroll
    for (int j = 0; j < 4; ++j) b_base[j] = (wc * 64 + j * 16 + lr) * 64;
    const int xs0 = ((hk)     ^ x7) << 3;   // kk=0: c8 = hk
    const int xs1 = ((hk + 4) ^ x7) << 3;   // kk=1: c8 = 4+hk

    f32x4 acc[4][4];
    #pragma unroll
    for (int i = 0; i < 4; ++i)
        #pragma unroll
        for (int j = 0; j < 4; ++j)
            acc[i][j] = (f32x4){0.f, 0.f, 0.f, 0.f};

    const int NT = K >> 6;

    auto STAGE = [&](int buf, int t) {
        const u16* pa = gA + (size_t)t * 64;
        const u16* pb = gB + (size_t)t * 64;
        #pragma unroll
        for (int i = 0; i < 4; ++i)
            async_copy16(pa + (size_t)i * 32 * K, &As[buf][i * 2048 + wid * 512]);
        #pragma unroll
        for (int i = 0; i < 4; ++i)
            async_copy16(pb + (size_t)i * 32 * K, &Bs[buf][i * 2048 + wid * 512]);
    };

    STAGE(0, 0);
    STAGE(1, 1);

    for (int t = 0; t < NT; ++t) {
        const int buf = t & 1;
        // wait for tile t's 8 loads; keep tile t+1's 8 in flight (never drain mid-loop)
        if (t + 1 < NT) asm volatile("s_waitcnt vmcnt(8)" ::: "memory");
        else            asm volatile("s_waitcnt vmcnt(0)" ::: "memory");
        __builtin_amdgcn_s_barrier();

        bf16x8 af[4][2], bg[4][2];
        #pragma unroll
        for (int i = 0; i < 4; ++i) {
            af[i][0] = *(const bf16x8*)&As[buf][a_base[i] + xs0];
            af[i][1] = *(const bf16x8*)&As[buf][a_base[i] + xs1];
        }
        #pragma unroll
        for (int j = 0; j < 4; ++j) {
            bg[j][0] = *(const bf16x8*)&Bs[buf][b_base[j] + xs0];
            bg[j][1] = *(const bf16x8*)&Bs[buf][b_base[j] + xs1];
        }
        asm volatile("s_waitcnt lgkmcnt(0)" ::: "memory");
        __builtin_amdgcn_sched_barrier(0);
        __builtin_amdgcn_s_barrier();          // all waves done reading buf -> safe to overwrite

        if (t + 2 < NT) STAGE(buf, t + 2);     // overlaps with MFMA below

        __builtin_amdgcn_s_setprio(1);
        #pragma unroll
        for (int kk = 0; kk < 2; ++kk)
            #pragma unroll
            for (int i = 0; i < 4; ++i)
                #pragma unroll
                for (int j = 0; j < 4; ++j)
                    acc[i][j] = __builtin_amdgcn_mfma_f32_16x16x32_bf16(
                        af[i][kk], bg[j][kk], acc[i][j], 0, 0, 0);
        __builtin_amdgcn_s_setprio(0);
    }

    // epilogue: D[row=(lane>>4)*4+reg][col=lane&15]; relu; bf16 store
    const int er = hk * 4;
    #pragma unroll
    for (int i = 0; i < 4; ++i) {
        #pragma unroll
        for (int j = 0; j < 4; ++j) {
            int r = row0 + wr * 64 + i * 16 + er;
            int c = col0 + wc * 64 + j * 16 + lr;
            #pragma unroll
            for (int b2 = 0; b2 < 4; ++b2) {
                float x = acc[i][j][b2];
                x = x > 0.f ? x : 0.f;
                H[(size_t)(r + b2) * N + c] = f2bf(x);
            }
        }
    }
}

// ---------------- BatchNorm (training-mode, biased var) on bf16 H ----------------

__global__ __launch_bounds__(256) void bn_partial(
    const u16* __restrict__ H, float* __restrict__ part)
{
    int c  = blockIdx.x * 256 + threadIdx.x;
    int r0 = blockIdx.y * 64;
    float s = 0.f, s2 = 0.f;
    #pragma unroll 8
    for (int r = 0; r < 64; ++r) {
        float v = bf2f(H[(size_t)(r0 + r) * 1024 + c]);
        s += v; s2 += v * v;
    }
    part[(size_t)blockIdx.y * 1024 + c] = s;
    part[131072 + (size_t)blockIdx.y * 1024 + c] = s2;
}

__global__ __launch_bounds__(256) void bn_finalize(
    const float* __restrict__ part, const float* __restrict__ gamma,
    const float* __restrict__ beta, float* __restrict__ ss)
{
    int c = blockIdx.x * 256 + threadIdx.x;
    float s = 0.f, s2 = 0.f;
    for (int i = 0; i < 128; ++i) {
        s  += part[(size_t)i * 1024 + c];
        s2 += part[131072 + (size_t)i * 1024 + c];
    }
    float mean = s * (1.0f / 8192.0f);
    float var  = fmaxf(s2 * (1.0f / 8192.0f) - mean * mean, 0.f);
    float sc   = gamma[c] * rsqrtf(var + 1e-5f);
    ss[c]        = sc;
    ss[1024 + c] = beta[c] - mean * sc;
}

// apply: A = bf16(H*scale + shift), 8 elems/thread
__global__ __launch_bounds__(256) void bn_apply(
    const u16* __restrict__ H, const float* __restrict__ ss,
    u16* __restrict__ Aout)
{
    int i = blockIdx.x * 256 + threadIdx.x;     // group of 8
    int c = (i * 8) & 1023;
    ushort8 h = *(const ushort8*)(H + (size_t)i * 8);
    float4 sc0 = *(const float4*)(ss + c);
    float4 sc1 = *(const float4*)(ss + c + 4);
    float4 sh0 = *(const float4*)(ss + 1024 + c);
    float4 sh1 = *(const float4*)(ss + 1024 + c + 4);
    ushort8 o;
    o[0] = f2bf(bf2f(h[0]) * sc0.x + sh0.x);
    o[1] = f2bf(bf2f(h[1]) * sc0.y + sh0.y);
    o[2] = f2bf(bf2f(h[2]) * sc0.z + sh0.z);
    o[3] = f2bf(bf2f(h[3]) * sc0.w + sh0.w);
    o[4] = f2bf(bf2f(h[4]) * sc1.x + sh1.x);
    o[5] = f2bf(bf2f(h[5]) * sc1.y + sh1.y);
    o[6] = f2bf(bf2f(h[6]) * sc1.z + sh1.z);
    o[7] = f2bf(bf2f(h[7]) * sc1.w + sh1.w);
    *(ushort8*)(Aout + (size_t)i * 8) = o;
}

// ---------------- head: out[8192,10] = A @ W4T (K=1024) ----------------

__global__ __launch_bounds__(256) void head_kernel(
    const u16* __restrict__ A, const u16* __restrict__ W4T,
    float* __restrict__ out)
{
    const int lane = threadIdx.x & 63;
    const int wid  = threadIdx.x >> 6;
    const int r    = blockIdx.x * 4 + wid;

    float acc[10];
    #pragma unroll
    for (int c = 0; c < 10; c++) acc[c] = 0.f;

    #pragma unroll
    for (int j = 0; j < 16; ++j) {
        int k = j * 64 + lane;
        float a = bf2f(A[(size_t)r * 1024 + k]);
        ushort8 w0 = *(const ushort8*)(W4T + (size_t)k * 16);
        acc[0] += a * bf2f(w0[0]); acc[1] += a * bf2f(w0[1]);
        acc[2] += a * bf2f(w0[2]); acc[3] += a * bf2f(w0[3]);
        acc[4] += a * bf2f(w0[4]); acc[5] += a * bf2f(w0[5]);
        acc[6] += a * bf2f(w0[6]); acc[7] += a * bf2f(w0[7]);
        u16 w8 = W4T[(size_t)k * 16 + 8];
        u16 w9 = W4T[(size_t)k * 16 + 9];
        acc[8] += a * bf2f(w8);    acc[9] += a * bf2f(w9);
    }
    #pragma unroll
    for (int c = 0; c < 10; c++) {
        float s = acc[c];
        #pragma unroll
        for (int off = 32; off > 0; off >>= 1) s += __shfl_xor(s, off, 64);
        acc[c] = s;
    }
    if (lane == 0) {
        #pragma unroll
        for (int c = 0; c < 10; c++) out[(size_t)r * 10 + c] = acc[c];
    }
}

// ---------------- launch ----------------

extern "C" void kernel_launch(void* const* d_in, const int* in_sizes, int n_in,
                              void* d_out, int out_size, void* d_ws, size_t ws_size,
                              hipStream_t stream) {
    const float* x  = (const float*)d_in[0];
    const float* W1 = (const float*)d_in[1];
    const float* W2 = (const float*)d_in[2];
    const float* W3 = (const float*)d_in[3];
    const float* W4 = (const float*)d_in[4];
    const float* g1 = (const float*)d_in[5];
    const float* b1 = (const float*)d_in[6];
    const float* g2 = (const float*)d_in[7];
    const float* b2 = (const float*)d_in[8];
    const float* g3 = (const float*)d_in[9];
    const float* b3 = (const float*)d_in[10];
    float* out = (float*)d_out;

    char* ws = (char*)d_ws;
    u16*   Xb   = (u16*)  (ws + 0);           // 50,331,648 (x bf16; reused as A)
    u16*   Hb   = (u16*)  (ws + 50331648);    // 16,777,216 (bf16 H)
    u16*   W1b  = (u16*)  (ws + 67108864);    //  6,291,456
    u16*   W2b  = (u16*)  (ws + 73400320);    //  2,097,152
    u16*   W3b  = (u16*)  (ws + 75497472);    //  2,097,152
    u16*   W4T  = (u16*)  (ws + 77594624);    //     32,768
    float* part = (float*)(ws + 77627392);    //  1,048,576
    float* ss   = (float*)(ws + 78675968);    //      8,192
    u16*   A    = Xb;

    f32_to_bf16_kernel<<<12288, 256, 0, stream>>>(x, Xb, 3145728);
    binarize_kernel<<<1536, 256, 0, stream>>>(W1, W1b, 393216);
    binarize_kernel<<<512, 256, 0, stream>>>(W2, W2b, 131072);
    binarize_kernel<<<512, 256, 0, stream>>>(W3, W3b, 131072);
    build_w4t<<<64, 256, 0, stream>>>(W4, W4T);

    dim3 gemm_grid(64, 8);   // M/128, N/128
    dim3 bn_grid(4, 128);

    gemm_bt_relu_bn<<<gemm_grid, 256, 0, stream>>>(Xb, W1b, Hb, 8192, 1024, 3072);
    bn_partial<<<bn_grid, 256, 0, stream>>>(Hb, part);
    bn_finalize<<<4, 256, 0, stream>>>(part, g1, b1, ss);
    bn_apply<<<4096, 256, 0, stream>>>(Hb, ss, A);

    gemm_bt_relu_bn<<<gemm_grid, 256, 0, stream>>>(A, W2b, Hb, 8192, 1024, 1024);
    bn_partial<<<bn_grid, 256, 0, stream>>>(Hb, part);
    bn_finalize<<<4, 256, 0, stream>>>(part, g2, b2, ss);
    bn_apply<<<4096, 256, 0, stream>>>(Hb, ss, A);

    gemm_bt_relu_bn<<<gemm_grid, 256, 0, stream>>>(A, W3b, Hb, 8192, 1024, 1024);
    bn_partial<<<bn_grid, 256, 0, stream>>>(Hb, part);
    bn_finalize<<<4, 256, 0, stream>>>(part, g3, b3, ss);
    bn_apply<<<4096, 256, 0, stream>>>(Hb, ss, A);

    head_kernel<<<2048, 256, 0, stream>>>(A, W4T, out);
}

// Round 3
// 191.140 us; speedup vs baseline: 1.4300x; 1.1048x over previous
//
#include <hip/hip_runtime.h>
#include <stdint.h>

typedef unsigned short u16;
typedef __attribute__((ext_vector_type(8))) unsigned short ushort8;
typedef __attribute__((ext_vector_type(4))) unsigned short ushort4v;
typedef __attribute__((ext_vector_type(8))) __bf16 bf16x8;
typedef __attribute__((ext_vector_type(4))) float f32x4;

__device__ __forceinline__ u16 f2bf(float f) {
    union { float f; unsigned int u; } v; v.f = f;
    unsigned int r = v.u + 0x7FFFu + ((v.u >> 16) & 1u);   // RNE
    return (u16)(r >> 16);
}
__device__ __forceinline__ float bf2f(u16 b) {
    union { unsigned int u; float f; } v; v.u = ((unsigned int)b) << 16;
    return v.f;
}

typedef __attribute__((address_space(1))) const uint32_t* gptr_t;
typedef __attribute__((address_space(3))) uint32_t* lptr_t;
__device__ __forceinline__ void async_copy16(const void* g, void* l) {
    __builtin_amdgcn_global_load_lds((gptr_t)g, (lptr_t)l, 16, 0, 0);
}

// ---------------- conversions ----------------

__global__ __launch_bounds__(256) void f32_to_bf16_kernel(
    const float* __restrict__ in, u16* __restrict__ out, int n8)
{
    int i = blockIdx.x * 256 + threadIdx.x;
    if (i >= n8) return;
    const float4* p = (const float4*)(in + (size_t)i * 8);
    float4 x0 = p[0], x1 = p[1];
    ushort8 o;
    o[0] = f2bf(x0.x); o[1] = f2bf(x0.y); o[2] = f2bf(x0.z); o[3] = f2bf(x0.w);
    o[4] = f2bf(x1.x); o[5] = f2bf(x1.y); o[6] = f2bf(x1.z); o[7] = f2bf(x1.w);
    *(ushort8*)(out + (size_t)i * 8) = o;
}

__global__ __launch_bounds__(256) void binarize_kernel(
    const float* __restrict__ in, u16* __restrict__ out, int n8)
{
    int i = blockIdx.x * 256 + threadIdx.x;
    if (i >= n8) return;
    const float4* p = (const float4*)(in + (size_t)i * 8);
    float4 x0 = p[0], x1 = p[1];
    ushort8 o;
    o[0] = x0.x >= 0.f ? 0x3F80 : 0xBF80;
    o[1] = x0.y >= 0.f ? 0x3F80 : 0xBF80;
    o[2] = x0.z >= 0.f ? 0x3F80 : 0xBF80;
    o[3] = x0.w >= 0.f ? 0x3F80 : 0xBF80;
    o[4] = x1.x >= 0.f ? 0x3F80 : 0xBF80;
    o[5] = x1.y >= 0.f ? 0x3F80 : 0xBF80;
    o[6] = x1.z >= 0.f ? 0x3F80 : 0xBF80;
    o[7] = x1.w >= 0.f ? 0x3F80 : 0xBF80;
    *(ushort8*)(out + (size_t)i * 8) = o;
}

// W4 [10][1024] f32 -> W4T [1024][16] bf16 (cols 10..15 zero), plain sign
__global__ __launch_bounds__(256) void build_w4t(
    const float* __restrict__ W4, u16* __restrict__ W4T)
{
    int idx = blockIdx.x * 256 + threadIdx.x;   // 16384 total
    int k = idx >> 4, c = idx & 15;
    u16 v = 0;
    if (c < 10) v = (W4[(size_t)c * 1024 + k] >= 0.f) ? 0x3F80 : 0xBF80;
    W4T[idx] = v;
}

// W' = bf16(sign(W)*sc_k), bias_n = sum_k sign(W)*sh_k.  W [1024][1024] f32.
// one wave per row, grid 256 x 256thr
__global__ __launch_bounds__(256) void rescale_w(
    const float* __restrict__ W, const float* __restrict__ ss,
    u16* __restrict__ Wp, float* __restrict__ bias)
{
    const int lane = threadIdx.x & 63;
    const int wid  = threadIdx.x >> 6;
    const int r    = blockIdx.x * 4 + wid;
    float bsum = 0.f;
    #pragma unroll
    for (int k0 = 0; k0 < 1024; k0 += 256) {
        int k = k0 + lane * 4;
        float4 w  = *(const float4*)(W + (size_t)r * 1024 + k);
        float4 sc = *(const float4*)(ss + k);
        float4 sh = *(const float4*)(ss + 1024 + k);
        ushort4v o;
        o[0] = f2bf(w.x >= 0.f ? sc.x : -sc.x);
        o[1] = f2bf(w.y >= 0.f ? sc.y : -sc.y);
        o[2] = f2bf(w.z >= 0.f ? sc.z : -sc.z);
        o[3] = f2bf(w.w >= 0.f ? sc.w : -sc.w);
        bsum += (w.x >= 0.f ? sh.x : -sh.x) + (w.y >= 0.f ? sh.y : -sh.y)
              + (w.z >= 0.f ? sh.z : -sh.z) + (w.w >= 0.f ? sh.w : -sh.w);
        *(ushort4v*)(Wp + (size_t)r * 1024 + k) = o;
    }
    #pragma unroll
    for (int off = 32; off; off >>= 1) bsum += __shfl_xor(bsum, off, 64);
    if (lane == 0) bias[r] = bsum;
}

// ---------------- GEMM: H = bf16(relu(A @ B^T + bias)), fused BN column stats ----------------
// A[M,K] bf16, B[N,K] bf16, H[M,N] bf16. 128x128 tile, BK=64, 4 waves,
// double-buffered LDS, counted vmcnt, T2 XOR-swizzle.
// Per-wave column partials (sum, sumsq over the wave's 64 rows) -> partS/partS2 [128][1024].

__global__ __launch_bounds__(256) void gemm_fused(
    const u16* __restrict__ A, const u16* __restrict__ B,
    u16* __restrict__ H, const float* __restrict__ bias,
    float* __restrict__ partS, float* __restrict__ partS2,
    int M, int N, int K)
{
    __shared__ __align__(16) u16 As[2][128 * 64];
    __shared__ __align__(16) u16 Bs[2][128 * 64];

    const int tid  = threadIdx.x;
    const int wid  = tid >> 6;
    const int lane = tid & 63;
    const int lr   = lane & 15;
    const int hk   = lane >> 4;
    const int x7   = lr & 7;
    const int wr   = wid >> 1;
    const int wc   = wid & 1;
    const int row0 = blockIdx.x * 128;
    const int col0 = blockIdx.y * 128;

    const int s_r = tid >> 3;
    const int s_c = (((tid & 7) ^ (s_r & 7)) << 3);
    const u16* gA = A + (size_t)(row0 + s_r) * K + s_c;
    const u16* gB = B + (size_t)(col0 + s_r) * K + s_c;

    int a_base[4], b_base[4];
    #pragma unroll
    for (int i = 0; i < 4; ++i) a_base[i] = (wr * 64 + i * 16 + lr) * 64;
    #pragma unroll
    for (int j = 0; j < 4; ++j) b_base[j] = (wc * 64 + j * 16 + lr) * 64;
    const int xs0 = ((hk)     ^ x7) << 3;
    const int xs1 = ((hk + 4) ^ x7) << 3;

    f32x4 acc[4][4];
    #pragma unroll
    for (int i = 0; i < 4; ++i)
        #pragma unroll
        for (int j = 0; j < 4; ++j)
            acc[i][j] = (f32x4){0.f, 0.f, 0.f, 0.f};

    const int NT = K >> 6;

    auto STAGE = [&](int buf, int t) {
        const u16* pa = gA + (size_t)t * 64;
        const u16* pb = gB + (size_t)t * 64;
        #pragma unroll
        for (int i = 0; i < 4; ++i)
            async_copy16(pa + (size_t)i * 32 * K, &As[buf][i * 2048 + wid * 512]);
        #pragma unroll
        for (int i = 0; i < 4; ++i)
            async_copy16(pb + (size_t)i * 32 * K, &Bs[buf][i * 2048 + wid * 512]);
    };

    STAGE(0, 0);
    STAGE(1, 1);

    for (int t = 0; t < NT; ++t) {
        const int buf = t & 1;
        if (t + 1 < NT) asm volatile("s_waitcnt vmcnt(8)" ::: "memory");
        else            asm volatile("s_waitcnt vmcnt(0)" ::: "memory");
        __builtin_amdgcn_s_barrier();

        bf16x8 af[4][2], bg[4][2];
        #pragma unroll
        for (int i = 0; i < 4; ++i) {
            af[i][0] = *(const bf16x8*)&As[buf][a_base[i] + xs0];
            af[i][1] = *(const bf16x8*)&As[buf][a_base[i] + xs1];
        }
        #pragma unroll
        for (int j = 0; j < 4; ++j) {
            bg[j][0] = *(const bf16x8*)&Bs[buf][b_base[j] + xs0];
            bg[j][1] = *(const bf16x8*)&Bs[buf][b_base[j] + xs1];
        }
        asm volatile("s_waitcnt lgkmcnt(0)" ::: "memory");
        __builtin_amdgcn_sched_barrier(0);
        __builtin_amdgcn_s_barrier();

        if (t + 2 < NT) STAGE(buf, t + 2);

        __builtin_amdgcn_s_setprio(1);
        #pragma unroll
        for (int kk = 0; kk < 2; ++kk)
            #pragma unroll
            for (int i = 0; i < 4; ++i)
                #pragma unroll
                for (int j = 0; j < 4; ++j)
                    acc[i][j] = __builtin_amdgcn_mfma_f32_16x16x32_bf16(
                        af[i][kk], bg[j][kk], acc[i][j], 0, 0, 0);
        __builtin_amdgcn_s_setprio(0);
    }

    // epilogue: D[row=hk*4+reg][col=lr]; +bias, relu, bf16 store, column stats
    const int er = hk * 4;
    #pragma unroll
    for (int j = 0; j < 4; ++j) {
        const int c = col0 + wc * 64 + j * 16 + lr;
        const float bj = bias ? bias[c] : 0.f;
        float s = 0.f, s2 = 0.f;
        #pragma unroll
        for (int i = 0; i < 4; ++i) {
            const int r = row0 + wr * 64 + i * 16 + er;
            #pragma unroll
            for (int b2 = 0; b2 < 4; ++b2) {
                float x = acc[i][j][b2] + bj;
                x = x > 0.f ? x : 0.f;
                s += x; s2 += x * x;
                H[(size_t)(r + b2) * N + c] = f2bf(x);
            }
        }
        // reduce across the 4 hk lane-groups sharing column c
        s  += __shfl_xor(s, 16, 64);  s  += __shfl_xor(s, 32, 64);
        s2 += __shfl_xor(s2, 16, 64); s2 += __shfl_xor(s2, 32, 64);
        if (hk == 0) {
            const int p = blockIdx.x * 2 + wr;
            partS [(size_t)p * 1024 + c] = s;
            partS2[(size_t)p * 1024 + c] = s2;
        }
    }
}

// ---------------- BN finalize: reduce 128 wave-partials per column ----------------

__global__ __launch_bounds__(256) void bn_finalize(
    const float* __restrict__ partS, const float* __restrict__ partS2,
    const float* __restrict__ gamma, const float* __restrict__ beta,
    float* __restrict__ ss)
{
    int c = blockIdx.x * 256 + threadIdx.x;
    float s = 0.f, s2 = 0.f;
    for (int i = 0; i < 128; ++i) {
        s  += partS [(size_t)i * 1024 + c];
        s2 += partS2[(size_t)i * 1024 + c];
    }
    float mean = s * (1.0f / 8192.0f);
    float var  = fmaxf(s2 * (1.0f / 8192.0f) - mean * mean, 0.f);
    float sc   = gamma[c] * rsqrtf(var + 1e-5f);
    ss[c]        = sc;
    ss[1024 + c] = beta[c] - mean * sc;
}

// ---------------- head: out[8192,10] = BN3(H) @ W4T (K=1024) ----------------

__global__ __launch_bounds__(256) void head_kernel(
    const u16* __restrict__ H, const u16* __restrict__ W4T,
    const float* __restrict__ ss, float* __restrict__ out)
{
    const int lane = threadIdx.x & 63;
    const int wid  = threadIdx.x >> 6;
    const int r    = blockIdx.x * 4 + wid;

    float acc[10];
    #pragma unroll
    for (int c = 0; c < 10; c++) acc[c] = 0.f;

    #pragma unroll
    for (int j = 0; j < 16; ++j) {
        int k = j * 64 + lane;
        float a = fmaf(bf2f(H[(size_t)r * 1024 + k]), ss[k], ss[1024 + k]);
        ushort8 w0 = *(const ushort8*)(W4T + (size_t)k * 16);
        acc[0] += a * bf2f(w0[0]); acc[1] += a * bf2f(w0[1]);
        acc[2] += a * bf2f(w0[2]); acc[3] += a * bf2f(w0[3]);
        acc[4] += a * bf2f(w0[4]); acc[5] += a * bf2f(w0[5]);
        acc[6] += a * bf2f(w0[6]); acc[7] += a * bf2f(w0[7]);
        u16 w8 = W4T[(size_t)k * 16 + 8];
        u16 w9 = W4T[(size_t)k * 16 + 9];
        acc[8] += a * bf2f(w8);    acc[9] += a * bf2f(w9);
    }
    #pragma unroll
    for (int c = 0; c < 10; c++) {
        float s = acc[c];
        #pragma unroll
        for (int off = 32; off > 0; off >>= 1) s += __shfl_xor(s, off, 64);
        acc[c] = s;
    }
    if (lane == 0) {
        #pragma unroll
        for (int c = 0; c < 10; c++) out[(size_t)r * 10 + c] = acc[c];
    }
}

// ---------------- launch ----------------

extern "C" void kernel_launch(void* const* d_in, const int* in_sizes, int n_in,
                              void* d_out, int out_size, void* d_ws, size_t ws_size,
                              hipStream_t stream) {
    const float* x  = (const float*)d_in[0];
    const float* W1 = (const float*)d_in[1];
    const float* W2 = (const float*)d_in[2];
    const float* W3 = (const float*)d_in[3];
    const float* W4 = (const float*)d_in[4];
    const float* g1 = (const float*)d_in[5];
    const float* b1 = (const float*)d_in[6];
    const float* g2 = (const float*)d_in[7];
    const float* b2 = (const float*)d_in[8];
    const float* g3 = (const float*)d_in[9];
    const float* b3 = (const float*)d_in[10];
    float* out = (float*)d_out;

    char* ws = (char*)d_ws;
    u16*   Xb    = (u16*)  (ws + 0);           // 50,331,648 (x bf16; dead after gemm1)
    float* bias2 = (float*)(ws + 0);           // reuse Xb region post-gemm1
    float* bias3 = (float*)(ws + 4096);
    u16*   Hb0   = (u16*)  (ws + 50331648);    // 16,777,216
    u16*   Hb1   = (u16*)  (ws + 67108864);    // 16,777,216
    u16*   W1b   = (u16*)  (ws + 83886080);    //  6,291,456
    u16*   W2p   = (u16*)  (ws + 90177536);    //  2,097,152
    u16*   W3p   = (u16*)  (ws + 92274688);    //  2,097,152
    u16*   W4T   = (u16*)  (ws + 94371840);    //     32,768
    float* partS = (float*)(ws + 94404608);    //    524,288
    float* partS2= (float*)(ws + 94928896);    //    524,288
    float* ss    = (float*)(ws + 95453184);    //      8,192

    f32_to_bf16_kernel<<<12288, 256, 0, stream>>>(x, Xb, 3145728);
    binarize_kernel<<<1536, 256, 0, stream>>>(W1, W1b, 393216);
    build_w4t<<<64, 256, 0, stream>>>(W4, W4T);

    dim3 gemm_grid(64, 8);   // M/128, N/128

    // layer 1
    gemm_fused<<<gemm_grid, 256, 0, stream>>>(Xb, W1b, Hb0, nullptr, partS, partS2, 8192, 1024, 3072);
    bn_finalize<<<4, 256, 0, stream>>>(partS, partS2, g1, b1, ss);
    rescale_w<<<256, 256, 0, stream>>>(W2, ss, W2p, bias2);

    // layer 2
    gemm_fused<<<gemm_grid, 256, 0, stream>>>(Hb0, W2p, Hb1, bias2, partS, partS2, 8192, 1024, 1024);
    bn_finalize<<<4, 256, 0, stream>>>(partS, partS2, g2, b2, ss);
    rescale_w<<<256, 256, 0, stream>>>(W3, ss, W3p, bias3);

    // layer 3
    gemm_fused<<<gemm_grid, 256, 0, stream>>>(Hb1, W3p, Hb0, bias3, partS, partS2, 8192, 1024, 1024);
    bn_finalize<<<4, 256, 0, stream>>>(partS, partS2, g3, b3, ss);

    // head (BN3 applied on the fly)
    head_kernel<<<2048, 256, 0, stream>>>(Hb0, W4T, ss, out);
}